// Round 6
// baseline (535.176 us; speedup 1.0000x reference)
//
#include <hip/hip_runtime.h>
#include <math.h>

#define NB 16
#define SS 2048
#define DQ 128
#define SCALE 0.08838834764831845f  // 1/sqrt(128)

typedef __bf16 bf16x8 __attribute__((ext_vector_type(8)));
typedef unsigned short ushort8_t __attribute__((ext_vector_type(8)));
typedef float floatx4 __attribute__((ext_vector_type(4)));
typedef unsigned long long u64;

// fp32 -> bf16 round-to-nearest-even (finite randn inputs; no NaN path)
__device__ __forceinline__ unsigned short f2bf(float x) {
  unsigned int u = __float_as_uint(x);
  u += 0x7fffu + ((u >> 16) & 1u);
  return (unsigned short)(u >> 16);
}
union FragU { ushort8_t u; bf16x8 b; };
__device__ __forceinline__ bf16x8 ld_frag(const unsigned short* p) {
  FragU t; t.u = *(const ushort8_t*)p; return t.b;
}
__device__ __forceinline__ floatx4 mfma16(bf16x8 a, bf16x8 b, floatx4 c) {
  return __builtin_amdgcn_mfma_f32_16x16x32_bf16(a, b, c, 0, 0, 0);
}

// LDS-only barrier: waits DS ops, leaves global loads (vmcnt) IN FLIGHT.
__device__ __forceinline__ void bar_lds() {
  asm volatile("s_waitcnt lgkmcnt(0)\n\ts_barrier" ::: "memory");
}

// d_out scratch layout per batch b (each row = DQ floats):
//   rows 16..31: colsum accumulator (2048 floats)
//   rows 64m..64m+15: replicated Linv strips (written by combine_linv)
// d_ws: Mbits[b][q][kt] u64, kt = k/64; bit kl = attn_mask[b][q][kt*64+kl].
//   Size NB*SS*32*8 = 8.4 MB.

// ---------------------------------------------------------------------------
__global__ void zero_accum(float* __restrict__ O) {
  float* p = O + (size_t)blockIdx.x * SS * DQ + 16 * DQ;
#pragma unroll
  for (int i = 0; i < 8; ++i) p[threadIdx.x + 256 * i] = 0.f;
}

// ---------------------------------------------------------------------------
// Compress mask: 268 MB int32 -> 8.4 MB bit-words. Pure streaming kernel.
// One wave per q-row: issue all 32 dword loads first (8 KB in flight per
// wave -> BW-saturating), then 32 ballots; lanes 0..31 store one u64 each
// (coalesced 256 B row store).
// ---------------------------------------------------------------------------
__global__ __launch_bounds__(256) void compress_mask(
    const int* __restrict__ M, u64* __restrict__ Mb)
{
  const int b = blockIdx.x;
  const int q = blockIdx.y * 4 + (threadIdx.x >> 6);
  const int lane = threadIdx.x & 63;

  const int* row = M + ((size_t)b * SS + q) * SS;
  int v[32];
#pragma unroll
  for (int kt = 0; kt < 32; ++kt) v[kt] = row[kt * 64 + lane];

  u64 w = 0;
#pragma unroll
  for (int kt = 0; kt < 32; ++kt) {
    u64 bal = __ballot(v[kt] != 0);
    if (lane == kt) w = bal;
  }
  u64* orow = Mb + ((size_t)b * SS + q) * 32;
  if (lane < 32) orow[lane] = w;
}

// ---------------------------------------------------------------------------
// Pass 1 (bits): colsum[b][k] += sum_q exp(masked_score).
// ROUND-1 verbatim structure (161 µs-verified barrier-paced staging); the
// only changes: mask int4 x4 prefetch -> one u64 word, and NO E write.
// grid (32 ktiles, NB, 4 qchunks) = 2048 blocks, 256 thr.
// ---------------------------------------------------------------------------
__global__ __launch_bounds__(256, 4) void pass1_bits(
    const float* __restrict__ Q, const float* __restrict__ K,
    const u64* __restrict__ Mb, float* __restrict__ O)
{
  const int kt  = blockIdx.x;             // k-tile index (k0 = 64*kt)
  const int k0  = kt * 64;
  const int b   = blockIdx.y;
  const int qc  = blockIdx.z;
  const int tid = threadIdx.x;
  const int w = tid >> 6, lane = tid & 63, l15 = lane & 15, quad = lane >> 4;

  __shared__ unsigned short Kbf[64][136];   // 17.4 KB (resident)
  __shared__ unsigned short Qbf[64][136];   // 17.4 KB (per q-iter)
  __shared__ float red[4][64];

  const float* Qb = Q + (size_t)b * SS * DQ;
  const float* Kb = K + (size_t)b * SS * DQ;
  const u64*   Mbb = Mb + (size_t)b * SS * 32 + kt;   // + qrow*32 per row

  const int srow = tid >> 5;              // staging row base (this thread)
  const int sc4  = (tid & 31) * 4;        // staging col (floats)

  // stage K strip 64 x 128 -> bf16 (resident)
#pragma unroll
  for (int r = 0; r < 8; ++r) {
    int row = srow + r * 8;
    float4 v = *(const float4*)(Kb + (size_t)(k0 + row) * DQ + sc4);
    *(ushort4*)&Kbf[row][sc4] = make_ushort4(f2bf(v.x), f2bf(v.y), f2bf(v.z), f2bf(v.w));
  }

  const int qlane = 16 * w + l15;         // wave-local q row within iter tile

  // prologue: prefetch q-tile 0 + its mask word into registers
  float4 qreg[8];
  u64 mw_nxt;
  {
    const int q0 = qc * 512;
#pragma unroll
    for (int r = 0; r < 8; ++r)
      qreg[r] = *(const float4*)(Qb + (size_t)(q0 + srow + r * 8) * DQ + sc4);
    mw_nxt = Mbb[(size_t)(q0 + qlane) * 32];
  }

  float colacc[16];
#pragma unroll
  for (int t = 0; t < 16; ++t) colacc[t] = 0.f;

  for (int qi = 0; qi < 8; ++qi) {
    bar_lds();  // prev Qbf readers done (1st iter: K-staging ds_writes drained)
    u64 mw = mw_nxt;
    // store prefetched Q regs -> LDS (vmcnt waits are fine-grained here)
#pragma unroll
    for (int r = 0; r < 8; ++r) {
      float4 v = qreg[r];
      *(ushort4*)&Qbf[srow + r * 8][sc4] =
          make_ushort4(f2bf(v.x), f2bf(v.y), f2bf(v.z), f2bf(v.w));
    }
    bar_lds();  // Qbf ready; prefetch below flies across the next barrier
    if (qi < 7) {
      const int qn = qc * 512 + (qi + 1) * 64;
#pragma unroll
      for (int r = 0; r < 8; ++r)
        qreg[r] = *(const float4*)(Qb + (size_t)(qn + srow + r * 8) * DQ + sc4);
      mw_nxt = Mbb[(size_t)(qn + qlane) * 32];
    }

    floatx4 acc[4];
#pragma unroll
    for (int i = 0; i < 4; ++i) acc[i] = (floatx4){0.f, 0.f, 0.f, 0.f};
#pragma unroll
    for (int d0 = 0; d0 < DQ; d0 += 32) {
      bf16x8 bq = ld_frag(&Qbf[qlane][d0 + quad * 8]);
#pragma unroll
      for (int i = 0; i < 4; ++i) {
        bf16x8 ak = ld_frag(&Kbf[16 * i + l15][d0 + quad * 8]);
        acc[i] = mfma16(ak, bq, acc[i]);
      }
    }
    // epilogue: C row = k_local = 16i+quad*4+r, col = q = qlane
#pragma unroll
    for (int i = 0; i < 4; ++i) {
#pragma unroll
      for (int r = 0; r < 4; ++r) {
        int m = (int)(mw >> (16 * i + quad * 4 + r)) & 1;
        float s = m ? 1e-9f : acc[i][r] * SCALE;
        colacc[i * 4 + r] += __expf(s);
      }
    }
  }

  // reduce over the 16 q-lanes (l15 dimension)
#pragma unroll
  for (int t = 0; t < 16; ++t) {
    colacc[t] += __shfl_xor(colacc[t], 1, 64);
    colacc[t] += __shfl_xor(colacc[t], 2, 64);
    colacc[t] += __shfl_xor(colacc[t], 4, 64);
    colacc[t] += __shfl_xor(colacc[t], 8, 64);
  }
  if (l15 == 0) {
#pragma unroll
    for (int i = 0; i < 4; ++i)
#pragma unroll
      for (int r = 0; r < 4; ++r)
        red[w][16 * i + quad * 4 + r] = colacc[i * 4 + r];
  }
  bar_lds();
  if (tid < 64) {
    float s = red[0][tid] + red[1][tid] + red[2][tid] + red[3][tid];
    atomicAdd(O + (size_t)b * SS * DQ + 16 * DQ + k0 + tid, s);
  }
}

// ---------------------------------------------------------------------------
// Combine: inv = 1/colsum; write replicated strips. grid (NB, 8), 256 thr.
// ---------------------------------------------------------------------------
__global__ void combine_linv(float* __restrict__ O) {
  const int b  = blockIdx.x;
  const int jb = blockIdx.y * 4;
  float* Ob = O + (size_t)b * SS * DQ;
#pragma unroll
  for (int it = 0; it < 8; ++it) {
    int k = threadIdx.x + 256 * it;
    float inv = 1.0f / Ob[16 * DQ + k];
#pragma unroll
    for (int j = 0; j < 4; ++j)
      Ob[(size_t)(64 * (jb + j)) * DQ + k] = inv;
  }
}

// ---------------------------------------------------------------------------
// Pass 2 (bits): recompute QK + exp with the 8 MB bit-mask (no 268 MB raw
// mask, no 134 MB E). Structure = verified pass2_out verbatim; only the
// mask path changed (one u64 load per k-tile per lane).
// grid (32, NB) = 512 blocks, 256 thr.
// ---------------------------------------------------------------------------
__global__ __launch_bounds__(256, 2) void pass2_bits(
    const float* __restrict__ Q, const float* __restrict__ K,
    const float* __restrict__ V, const u64* __restrict__ Mb,
    float* __restrict__ O)
{
  const int b = blockIdx.y, q0 = blockIdx.x * 64;
  const int tid = threadIdx.x;
  const int w = tid >> 6, lane = tid & 63, l15 = lane & 15, quad = lane >> 4;

  __shared__ unsigned short Kbf[64][136];  // 17.4 KB
  __shared__ unsigned short Es[64][72];    //  9.2 KB  [q][k], wave-private rows
  __shared__ unsigned short Wt[128][72];   // 18.4 KB  [d][k^swz]
  __shared__ float Li[SS];                 //  8.0 KB

  const float* Qb = Q + (size_t)b * SS * DQ;
  const float* Kb = K + (size_t)b * SS * DQ;
  const float* Vb = V + (size_t)b * SS * DQ;

  const int srow = tid >> 5;
  const int sc4  = (tid & 31) * 4;

  // preload replicated Linv strip from own territory (before any O write)
  {
    const float* src = O + ((size_t)b * SS + q0) * DQ;
#pragma unroll
    for (int r = 0; r < 2; ++r) {
      int idx = (tid + r * 256) * 4;
      *(float4*)&Li[idx] = *(const float4*)(src + idx);
    }
  }
  // Q fragments in registers: this lane's q row, 4 fragments over d
  FragU qf[4];
  {
    const float* qrow = Qb + (size_t)(q0 + 16 * w + l15) * DQ;
#pragma unroll
    for (int i = 0; i < 4; ++i) {
      float4 a = *(const float4*)(qrow + 32 * i + quad * 8);
      float4 c = *(const float4*)(qrow + 32 * i + quad * 8 + 4);
      qf[i].u = (ushort8_t){f2bf(a.x), f2bf(a.y), f2bf(a.z), f2bf(a.w),
                            f2bf(c.x), f2bf(c.y), f2bf(c.z), f2bf(c.w)};
    }
  }

  floatx4 accO[8];
#pragma unroll
  for (int j = 0; j < 8; ++j) accO[j] = (floatx4){0.f, 0.f, 0.f, 0.f};

  const u64* brow = Mb + (size_t)(b * SS + q0 + 16 * w + l15) * 32;

  // prologue: prefetch k-tile 0 (K rows, V row-pairs, mask word)
  float4 kreg[8], vreg[8];
  u64 mw_nxt;
  const int vk2 = (tid >> 5) * 2;   // V row-pair base for this thread (0..14)
  {
#pragma unroll
    for (int r = 0; r < 8; ++r)
      kreg[r] = *(const float4*)(Kb + (size_t)(srow + r * 8) * DQ + sc4);
#pragma unroll
    for (int r = 0; r < 4; ++r) {
      int k2 = vk2 + r * 16;
      vreg[2 * r]     = *(const float4*)(Vb + (size_t)(k2)     * DQ + sc4);
      vreg[2 * r + 1] = *(const float4*)(Vb + (size_t)(k2 + 1) * DQ + sc4);
    }
    mw_nxt = brow[0];
  }

  for (int k0 = 0; k0 < SS; k0 += 64) {
    bar_lds();  // prev iter's Kbf/Wt readers done; Li ds_writes drained
    u64 mw = mw_nxt;

    // store prefetched K -> Kbf (bf16)
#pragma unroll
    for (int r = 0; r < 8; ++r) {
      float4 v = kreg[r];
      *(ushort4*)&Kbf[srow + r * 8][sc4] =
          make_ushort4(f2bf(v.x), f2bf(v.y), f2bf(v.z), f2bf(v.w));
    }
    // store prefetched V -> Wt (transposed, xor-swizzled, ushort2 pairs)
#pragma unroll
    for (int r = 0; r < 4; ++r) {
      int k2 = vk2 + r * 16;
      float fa[4] = {vreg[2*r].x, vreg[2*r].y, vreg[2*r].z, vreg[2*r].w};
      float fb[4] = {vreg[2*r+1].x, vreg[2*r+1].y, vreg[2*r+1].z, vreg[2*r+1].w};
#pragma unroll
      for (int i = 0; i < 4; ++i) {
        int d  = sc4 + i;
        int kk = k2 ^ ((((unsigned)d >> 2) & 7) << 3);   // xor on k-bits 3..5
        *(ushort2*)&Wt[d][kk] = make_ushort2(f2bf(fa[i]), f2bf(fb[i]));
      }
    }
    bar_lds();  // LDS ready; the prefetch below stays in flight across iters

    if (k0 + 64 < SS) {
      const int kn = k0 + 64;
#pragma unroll
      for (int r = 0; r < 8; ++r)
        kreg[r] = *(const float4*)(Kb + (size_t)(kn + srow + r * 8) * DQ + sc4);
#pragma unroll
      for (int r = 0; r < 4; ++r) {
        int k2 = vk2 + r * 16;
        vreg[2 * r]     = *(const float4*)(Vb + (size_t)(kn + k2)     * DQ + sc4);
        vreg[2 * r + 1] = *(const float4*)(Vb + (size_t)(kn + k2 + 1) * DQ + sc4);
      }
      mw_nxt = brow[(kn >> 6)];
    }

    // QK: C row = k_local = 16j+quad*4+r, col = q = q0+16w+l15
    floatx4 acc[4];
#pragma unroll
    for (int j = 0; j < 4; ++j) acc[j] = (floatx4){0.f, 0.f, 0.f, 0.f};
#pragma unroll
    for (int i = 0; i < 4; ++i) {
      bf16x8 bq = qf[i].b;
#pragma unroll
      for (int j = 0; j < 4; ++j) {
        bf16x8 ak = ld_frag(&Kbf[16 * j + l15][32 * i + quad * 8]);
        acc[j] = mfma16(ak, bq, acc[j]);
      }
    }
    // epilogue: mask+exp, fold Linv, write Es (own wave's rows only)
#pragma unroll
    for (int j = 0; j < 4; ++j) {
      float4 liv = *(const float4*)&Li[k0 + 16 * j + quad * 4];
      float lv[4] = {liv.x, liv.y, liv.z, liv.w};
      unsigned short es[4];
#pragma unroll
      for (int r = 0; r < 4; ++r) {
        int m = (int)(mw >> (16 * j + quad * 4 + r)) & 1;
        float s = m ? 1e-9f : acc[j][r] * SCALE;
        es[r] = f2bf(__expf(s) * lv[r]);
      }
      *(ushort4*)&Es[16 * w + l15][16 * j + quad * 4] =
          make_ushort4(es[0], es[1], es[2], es[3]);
    }
    // PV (no barrier: Es rows written & read by the same wave; lgkm ordering)
#pragma unroll
    for (int c = 0; c < 2; ++c) {
      bf16x8 be = ld_frag(&Es[16 * w + l15][32 * c + quad * 8]);
#pragma unroll
      for (int j = 0; j < 8; ++j) {
        int d  = 16 * j + l15;
        int kk = (32 * c + quad * 8) ^ ((((unsigned)d >> 2) & 7) << 3);
        bf16x8 aw = ld_frag(&Wt[d][kk]);
        accO[j] = mfma16(aw, be, accO[j]);
      }
    }
  }

  // write O: C row = d = 16j+quad*4+r, col = q = q0+16w+l15 -> float4 stores
#pragma unroll
  for (int j = 0; j < 8; ++j) {
    float* op = O + ((size_t)b * SS + q0 + 16 * w + l15) * DQ + 16 * j + quad * 4;
    *(float4*)op = make_float4(accO[j][0], accO[j][1], accO[j][2], accO[j][3]);
  }
}

// ---------------------------------------------------------------------------
// FALLBACK path (no workspace): raw-mask pass1 + recompute pass2, verified.
// ---------------------------------------------------------------------------
__global__ __launch_bounds__(256, 4) void pass1_colsum(
    const float* __restrict__ Q, const float* __restrict__ K,
    const int* __restrict__ M, float* __restrict__ O)
{
  const int k0  = blockIdx.x * 64;
  const int b   = blockIdx.y;
  const int qc  = blockIdx.z;
  const int tid = threadIdx.x;
  const int w = tid >> 6, lane = tid & 63, l15 = lane & 15, quad = lane >> 4;

  __shared__ unsigned short Kbf[64][136];
  __shared__ unsigned short Qbf[64][136];
  __shared__ float red[4][64];

  const float* Qb = Q + (size_t)b * SS * DQ;
  const float* Kb = K + (size_t)b * SS * DQ;
  const int*   Mb = M + (size_t)b * SS * SS;

  const int srow = tid >> 5;
  const int sc4  = (tid & 31) * 4;

#pragma unroll
  for (int r = 0; r < 8; ++r) {
    int row = srow + r * 8;
    float4 v = *(const float4*)(Kb + (size_t)(k0 + row) * DQ + sc4);
    *(ushort4*)&Kbf[row][sc4] = make_ushort4(f2bf(v.x), f2bf(v.y), f2bf(v.z), f2bf(v.w));
  }

  const int qlane = 16 * w + l15;

  float4 qreg[8];
  int4 mv_nxt[4];
  {
    const int q0 = qc * 512;
#pragma unroll
    for (int r = 0; r < 8; ++r)
      qreg[r] = *(const float4*)(Qb + (size_t)(q0 + srow + r * 8) * DQ + sc4);
#pragma unroll
    for (int i = 0; i < 4; ++i)
      mv_nxt[i] = *(const int4*)(Mb + (size_t)(q0 + qlane) * SS + k0 + 16 * i + quad * 4);
  }

  float colacc[16];
#pragma unroll
  for (int t = 0; t < 16; ++t) colacc[t] = 0.f;

  for (int qi = 0; qi < 8; ++qi) {
    bar_lds();
    int4 mv[4] = {mv_nxt[0], mv_nxt[1], mv_nxt[2], mv_nxt[3]};
#pragma unroll
    for (int r = 0; r < 8; ++r) {
      float4 v = qreg[r];
      *(ushort4*)&Qbf[srow + r * 8][sc4] =
          make_ushort4(f2bf(v.x), f2bf(v.y), f2bf(v.z), f2bf(v.w));
    }
    bar_lds();
    if (qi < 7) {
      const int qn = qc * 512 + (qi + 1) * 64;
#pragma unroll
      for (int r = 0; r < 8; ++r)
        qreg[r] = *(const float4*)(Qb + (size_t)(qn + srow + r * 8) * DQ + sc4);
#pragma unroll
      for (int i = 0; i < 4; ++i)
        mv_nxt[i] = *(const int4*)(Mb + (size_t)(qn + qlane) * SS + k0 + 16 * i + quad * 4);
    }

    floatx4 acc[4];
#pragma unroll
    for (int i = 0; i < 4; ++i) acc[i] = (floatx4){0.f, 0.f, 0.f, 0.f};
#pragma unroll
    for (int d0 = 0; d0 < DQ; d0 += 32) {
      bf16x8 bq = ld_frag(&Qbf[qlane][d0 + quad * 8]);
#pragma unroll
      for (int i = 0; i < 4; ++i) {
        bf16x8 ak = ld_frag(&Kbf[16 * i + l15][d0 + quad * 8]);
        acc[i] = mfma16(ak, bq, acc[i]);
      }
    }
#pragma unroll
    for (int i = 0; i < 4; ++i) {
      int mm[4] = {mv[i].x, mv[i].y, mv[i].z, mv[i].w};
#pragma unroll
      for (int r = 0; r < 4; ++r) {
        float s = mm[r] ? 1e-9f : acc[i][r] * SCALE;
        colacc[i * 4 + r] += __expf(s);
      }
    }
  }

#pragma unroll
  for (int t = 0; t < 16; ++t) {
    colacc[t] += __shfl_xor(colacc[t], 1, 64);
    colacc[t] += __shfl_xor(colacc[t], 2, 64);
    colacc[t] += __shfl_xor(colacc[t], 4, 64);
    colacc[t] += __shfl_xor(colacc[t], 8, 64);
  }
  if (l15 == 0) {
#pragma unroll
    for (int i = 0; i < 4; ++i)
#pragma unroll
      for (int r = 0; r < 4; ++r)
        red[w][16 * i + quad * 4 + r] = colacc[i * 4 + r];
  }
  bar_lds();
  if (tid < 64) {
    float s = red[0][tid] + red[1][tid] + red[2][tid] + red[3][tid];
    atomicAdd(O + (size_t)b * SS * DQ + 16 * DQ + k0 + tid, s);
  }
}

__global__ __launch_bounds__(256, 2) void pass2_out(
    const float* __restrict__ Q, const float* __restrict__ K,
    const float* __restrict__ V, const int* __restrict__ M,
    float* __restrict__ O)
{
  const int b = blockIdx.y, q0 = blockIdx.x * 64;
  const int tid = threadIdx.x;
  const int w = tid >> 6, lane = tid & 63, l15 = lane & 15, quad = lane >> 4;

  __shared__ unsigned short Kbf[64][136];
  __shared__ unsigned short Es[64][72];
  __shared__ unsigned short Wt[128][72];
  __shared__ float Li[SS];

  const float* Qb = Q + (size_t)b * SS * DQ;
  const float* Kb = K + (size_t)b * SS * DQ;
  const float* Vb = V + (size_t)b * SS * DQ;
  const int*   Mb = M + (size_t)b * SS * SS;

  const int srow = tid >> 5;
  const int sc4  = (tid & 31) * 4;

  {
    const float* src = O + ((size_t)b * SS + q0) * DQ;
#pragma unroll
    for (int r = 0; r < 2; ++r) {
      int idx = (tid + r * 256) * 4;
      *(float4*)&Li[idx] = *(const float4*)(src + idx);
    }
  }
  FragU qf[4];
  {
    const float* qrow = Qb + (size_t)(q0 + 16 * w + l15) * DQ;
#pragma unroll
    for (int i = 0; i < 4; ++i) {
      float4 a = *(const float4*)(qrow + 32 * i + quad * 8);
      float4 c = *(const float4*)(qrow + 32 * i + quad * 8 + 4);
      qf[i].u = (ushort8_t){f2bf(a.x), f2bf(a.y), f2bf(a.z), f2bf(a.w),
                            f2bf(c.x), f2bf(c.y), f2bf(c.z), f2bf(c.w)};
    }
  }

  floatx4 accO[8];
#pragma unroll
  for (int j = 0; j < 8; ++j) accO[j] = (floatx4){0.f, 0.f, 0.f, 0.f};

  const int* mrow = Mb + (size_t)(q0 + 16 * w + l15) * SS;

  float4 kreg[8], vreg[8];
  int4 mv_nxt[4];
  const int vk2 = (tid >> 5) * 2;
  {
#pragma unroll
    for (int r = 0; r < 8; ++r)
      kreg[r] = *(const float4*)(Kb + (size_t)(srow + r * 8) * DQ + sc4);
#pragma unroll
    for (int r = 0; r < 4; ++r) {
      int k2 = vk2 + r * 16;
      vreg[2 * r]     = *(const float4*)(Vb + (size_t)(k2)     * DQ + sc4);
      vreg[2 * r + 1] = *(const float4*)(Vb + (size_t)(k2 + 1) * DQ + sc4);
    }
#pragma unroll
    for (int j = 0; j < 4; ++j)
      mv_nxt[j] = *(const int4*)(mrow + 16 * j + quad * 4);
  }

  for (int k0 = 0; k0 < SS; k0 += 64) {
    bar_lds();
    int4 mv[4] = {mv_nxt[0], mv_nxt[1], mv_nxt[2], mv_nxt[3]};

#pragma unroll
    for (int r = 0; r < 8; ++r) {
      float4 v = kreg[r];
      *(ushort4*)&Kbf[srow + r * 8][sc4] =
          make_ushort4(f2bf(v.x), f2bf(v.y), f2bf(v.z), f2bf(v.w));
    }
#pragma unroll
    for (int r = 0; r < 4; ++r) {
      int k2 = vk2 + r * 16;
      float fa[4] = {vreg[2*r].x, vreg[2*r].y, vreg[2*r].z, vreg[2*r].w};
      float fb[4] = {vreg[2*r+1].x, vreg[2*r+1].y, vreg[2*r+1].z, vreg[2*r+1].w};
#pragma unroll
      for (int i = 0; i < 4; ++i) {
        int d  = sc4 + i;
        int kk = k2 ^ ((((unsigned)d >> 2) & 7) << 3);
        *(ushort2*)&Wt[d][kk] = make_ushort2(f2bf(fa[i]), f2bf(fb[i]));
      }
    }
    bar_lds();

    if (k0 + 64 < SS) {
      const int kn = k0 + 64;
#pragma unroll
      for (int r = 0; r < 8; ++r)
        kreg[r] = *(const float4*)(Kb + (size_t)(kn + srow + r * 8) * DQ + sc4);
#pragma unroll
      for (int r = 0; r < 4; ++r) {
        int k2 = vk2 + r * 16;
        vreg[2 * r]     = *(const float4*)(Vb + (size_t)(kn + k2)     * DQ + sc4);
        vreg[2 * r + 1] = *(const float4*)(Vb + (size_t)(kn + k2 + 1) * DQ + sc4);
      }
#pragma unroll
      for (int j = 0; j < 4; ++j)
        mv_nxt[j] = *(const int4*)(mrow + kn + 16 * j + quad * 4);
    }

    floatx4 acc[4];
#pragma unroll
    for (int j = 0; j < 4; ++j) acc[j] = (floatx4){0.f, 0.f, 0.f, 0.f};
#pragma unroll
    for (int i = 0; i < 4; ++i) {
      bf16x8 bq = qf[i].b;
#pragma unroll
      for (int j = 0; j < 4; ++j) {
        bf16x8 ak = ld_frag(&Kbf[16 * j + l15][32 * i + quad * 8]);
        acc[j] = mfma16(ak, bq, acc[j]);
      }
    }
#pragma unroll
    for (int j = 0; j < 4; ++j) {
      float4 liv = *(const float4*)&Li[k0 + 16 * j + quad * 4];
      float lv[4] = {liv.x, liv.y, liv.z, liv.w};
      int mm[4] = {mv[j].x, mv[j].y, mv[j].z, mv[j].w};
      unsigned short es[4];
#pragma unroll
      for (int r = 0; r < 4; ++r) {
        float s = mm[r] ? 1e-9f : acc[j][r] * SCALE;
        es[r] = f2bf(__expf(s) * lv[r]);
      }
      *(ushort4*)&Es[16 * w + l15][16 * j + quad * 4] =
          make_ushort4(es[0], es[1], es[2], es[3]);
    }
#pragma unroll
    for (int c = 0; c < 2; ++c) {
      bf16x8 be = ld_frag(&Es[16 * w + l15][32 * c + quad * 8]);
#pragma unroll
      for (int j = 0; j < 8; ++j) {
        int d  = 16 * j + l15;
        int kk = (32 * c + quad * 8) ^ ((((unsigned)d >> 2) & 7) << 3);
        bf16x8 aw = ld_frag(&Wt[d][kk]);
        accO[j] = mfma16(aw, be, accO[j]);
      }
    }
  }

#pragma unroll
  for (int j = 0; j < 8; ++j) {
    float* op = O + ((size_t)b * SS + q0 + 16 * w + l15) * DQ + 16 * j + quad * 4;
    *(float4*)op = make_float4(accO[j][0], accO[j][1], accO[j][2], accO[j][3]);
  }
}

// ---------------------------------------------------------------------------
extern "C" void kernel_launch(void* const* d_in, const int* in_sizes, int n_in,
                              void* d_out, int out_size, void* d_ws, size_t ws_size,
                              hipStream_t stream) {
  const float* Q = (const float*)d_in[0];
  const float* K = (const float*)d_in[1];
  const float* V = (const float*)d_in[2];
  const int*   M = (const int*)d_in[3];
  float* O = (float*)d_out;

  const size_t bneed = (size_t)NB * SS * 32 * sizeof(u64);   // 8.4 MB

  zero_accum<<<dim3(NB), 256, 0, stream>>>(O);
  if (d_ws != nullptr && ws_size >= bneed) {
    u64* Mb = (u64*)d_ws;
    compress_mask<<<dim3(NB, 512), 256, 0, stream>>>(M, Mb);
    pass1_bits<<<dim3(32, NB, 4), 256, 0, stream>>>(Q, K, Mb, O);
    combine_linv<<<dim3(NB, 8), 256, 0, stream>>>(O);
    pass2_bits<<<dim3(32, NB), 256, 0, stream>>>(Q, K, V, Mb, O);
  } else {
    pass1_colsum<<<dim3(32, NB, 4), 256, 0, stream>>>(Q, K, M, O);
    combine_linv<<<dim3(NB, 8), 256, 0, stream>>>(O);
    pass2_out<<<dim3(32, NB), 256, 0, stream>>>(Q, K, V, M, O);
  }
}